// Round 7
// baseline (102.881 us; speedup 1.0000x reference)
//
#include <hip/hip_runtime.h>

#define NSEQ   24
#define NBOX   196
#define NCTX   196
#define MAXLEN 6
#define EPSV   1e-6f
#define BS     32

#define TILES  25    // i-tiles per batch; 8 waves/block, 1 i per wave
#define K1T    512
#define NB4    49    // float4 chunks per 196-row
#define CROW   32    // caeT row stride in f32 (8 quads of 4)
#define CROWS  200   // 196 boxes + sentinel row 196 (+3 spare, all zero)

// ws layout: midx[BS][NBOX][NCTX] ints, then araw[BS][NBOX] floats
#define MIDX_ELEMS ((size_t)BS * NBOX * NCTX)

// add_raw[b,i] = kcls_i * sum_n sum_c caeT[midx[b,i,c]][n] * spo[b,e_n,i,c]
// caeT is the TRANSPOSED child matrix in LDS: row = box index k (plus zero
// sentinel row 196), column = child n, XOR-swizzled at quad granularity:
// element (k,n) lives at  k*CROW + 4*((n>>2) ^ (k&7)) + (n&3).
// A quad-read for (k, quad nb) is one ds_read_b128 at k*CROW + 4*(nb^(k&7)).
__global__ __launch_bounds__(K1T, 6) void step_compute(
    const float* __restrict__ src,      // ent (step 0) or ea (current state)
    float*       __restrict__ ea_copy,  // ea; written only when step==0
    const float* __restrict__ spo,      // [BS, NSEQ, NBOX, NCTX]
    const int*   __restrict__ ctx,      // [BS, NBOX, NCTX]
    const int*   __restrict__ roi_cls,  // [BS, NBOX]
    const float* __restrict__ rm,       // [BS, NBOX, NCTX]
    const int*   __restrict__ trav,     // [BS, MAXLEN]
    const int*   __restrict__ adj,      // [BS, NSEQ, NSEQ]
    int*         __restrict__ midx,     // ws
    float*       __restrict__ araw,     // ws
    int step, int mode)
{
    const int b    = blockIdx.x / TILES;
    const int tile = blockIdx.x % TILES;
    const int tid  = threadIdx.x;
    const int wave = tid >> 6;
    const int lane = tid & 63;

    __shared__ __align__(16) float caeT[CROWS * CROW];   // 25.6 KB
    __shared__ int s_childJ[NSEQ];

    // ---- fused ent -> ea copy (step 0; nothing reads ea this dispatch)
    if (step == 0) {
        const int total4 = BS * NSEQ * NBOX / 4;
        int idx = blockIdx.x * K1T + tid;
        if (idx < total4) ((float4*)ea_copy)[idx] = ((const float4*)src)[idx];
    }

    // ---- zero caeT (pad columns + sentinel row must be 0)
    {
        const float4 z = make_float4(0.f, 0.f, 0.f, 0.f);
        for (int t = tid; t < CROWS * CROW / 4; t += K1T)
            ((float4*)caeT)[t] = z;
    }

    // ---- wave-parallel adjacency parse (every wave, full exec, registers)
    const int p = trav[b * MAXLEN + step];
    int e = -1;
    if (p >= 0 && lane < NSEQ)
        e = adj[((size_t)b * NSEQ + p) * NSEQ + lane];
    const unsigned long long mask = __ballot(e >= 0);
    const int nch = __popcll(mask);
    if (nch == 0) return;   // uniform; no barrier crossed yet

    int ec, jc;   // lane n holds e/j of child n (lanes >= nch: child 0)
    {
        unsigned long long m = mask;
        const int lim = (lane < NSEQ) ? lane : NSEQ;
        for (int k = 0; k < lim; ++k) m &= (m - 1);
        const int j0 = __ffsll(mask) - 1;
        const int jn = m ? (__ffsll(m) - 1) : j0;
        jc = (lane < nch) ? jn : j0;
        ec = __shfl(e, jc);                       // full-exec shfl: safe
        if (wave == 0 && lane < nch) s_childJ[lane] = jc;  // publish for staging
    }
    __syncthreads();   // memset + s_childJ visible before scatter-stage

    // ---- stage child rows * kcls, transposed + swizzled (LDS child list:
    //      no shfl in this divergent-trip-count loop)
    for (int t = tid; t < nch * NBOX; t += K1T) {
        const int n = t / NBOX;
        const int k = t - n * NBOX;
        const int j = s_childJ[n];
        float v = src[((size_t)b * NSEQ + j) * NBOX + k];
        v = (roi_cls[b * NBOX + k] != -1) ? v : 0.f;
        caeT[k * CROW + 4 * ((n >> 2) ^ (k & 7)) + (n & 3)] = v;
    }
    __syncthreads();

    // ---- one i per wave
    const int i = tile * 8 + wave;
    if (i >= NBOX) return;

    float acc = 0.f;
    if (lane < NB4) {
        const size_t bi = (size_t)b * NBOX + i;
        int4 mi;
        if (mode == 2) {
            mi = ((const int4*)(midx + bi * NCTX))[lane];
        } else {
            const int4   ix = ((const int4*)  (ctx + bi * NCTX))[lane];
            const float4 m4 = ((const float4*)(rm  + bi * NCTX))[lane];
            mi.x = (m4.x != 0.f) ? ix.x : NBOX;
            mi.y = (m4.y != 0.f) ? ix.y : NBOX;
            mi.z = (m4.z != 0.f) ? ix.z : NBOX;
            mi.w = (m4.w != 0.f) ? ix.w : NBOX;
            if (mode == 1) ((int4*)(midx + bi * NCTX))[lane] = mi;
        }
        // per-component swizzled row base and k&7 class
        const int rbx = mi.x * CROW, c7x = mi.x & 7;
        const int rby = mi.y * CROW, c7y = mi.y & 7;
        const int rbz = mi.z * CROW, c7z = mi.z & 7;
        const int rbw = mi.w * CROW, c7w = mi.w & 7;

        const float* sb = spo + ((size_t)b * NSEQ * NBOX + i) * NCTX;
        const size_t st = (size_t)NBOX * NCTX;
        const int nq = (nch + 3) >> 2;

        float4 a4 = make_float4(0.f, 0.f, 0.f, 0.f);
        for (int nb = 0; nb < nq; ++nb) {
            const int n4 = nb << 2;
            // sources are lanes 0..27, all within the active prefix 0..48
            const int e0 = __shfl(ec, n4);
            const int e1 = __shfl(ec, n4 + 1);
            const int e2 = __shfl(ec, n4 + 2);
            const int e3 = __shfl(ec, n4 + 3);
            const float4 s0 = ((const float4*)(sb + (size_t)e0 * st))[lane];
            const float4 s1 = ((const float4*)(sb + (size_t)e1 * st))[lane];
            const float4 s2 = ((const float4*)(sb + (size_t)e2 * st))[lane];
            const float4 s3 = ((const float4*)(sb + (size_t)e3 * st))[lane];
            const float4 cx = *(const float4*)&caeT[rbx + ((nb ^ c7x) << 2)];
            const float4 cy = *(const float4*)&caeT[rby + ((nb ^ c7y) << 2)];
            const float4 cz = *(const float4*)&caeT[rbz + ((nb ^ c7z) << 2)];
            const float4 cw = *(const float4*)&caeT[rbw + ((nb ^ c7w) << 2)];
            a4.x = fmaf(cx.x, s0.x, a4.x); a4.x = fmaf(cx.y, s1.x, a4.x);
            a4.x = fmaf(cx.z, s2.x, a4.x); a4.x = fmaf(cx.w, s3.x, a4.x);
            a4.y = fmaf(cy.x, s0.y, a4.y); a4.y = fmaf(cy.y, s1.y, a4.y);
            a4.y = fmaf(cy.z, s2.y, a4.y); a4.y = fmaf(cy.w, s3.y, a4.y);
            a4.z = fmaf(cz.x, s0.z, a4.z); a4.z = fmaf(cz.y, s1.z, a4.z);
            a4.z = fmaf(cz.z, s2.z, a4.z); a4.z = fmaf(cz.w, s3.z, a4.z);
            a4.w = fmaf(cw.x, s0.w, a4.w); a4.w = fmaf(cw.y, s1.w, a4.w);
            a4.w = fmaf(cw.z, s2.w, a4.w); a4.w = fmaf(cw.w, s3.w, a4.w);
        }
        acc = (a4.x + a4.y) + (a4.z + a4.w);
    }

    #pragma unroll
    for (int off = 32; off >= 1; off >>= 1)
        acc += __shfl_down(acc, off, 64);
    if (lane == 0) {
        float kci = (roi_cls[b * NBOX + i] != -1) ? 1.0f : 0.0f;
        araw[b * NBOX + i] = kci * acc;
    }
}

// ------------------------------------------------- per-step: finalize + write
__global__ __launch_bounds__(256) void step_finalize(
    float*       __restrict__ ea,       // [BS, NSEQ, NBOX] in/out
    const float* __restrict__ araw,     // ws: [BS, NBOX]
    const float* __restrict__ wc,       // [BS, NSEQ, NBOX]
    const int*   __restrict__ roi_cls,  // [BS, NBOX]
    const int*   __restrict__ trav,     // [BS, MAXLEN]
    const int*   __restrict__ adj,      // [BS, NSEQ, NSEQ]
    int step)
{
    const int b   = blockIdx.x;
    const int tid = threadIdx.x;
    const int p   = trav[b * MAXLEN + step];

    int nch = 0;
    if (p >= 0) {
        const int* arow = adj + ((size_t)b * NSEQ + p) * NSEQ;
        for (int j = 0; j < NSEQ; ++j) nch += (arow[j] >= 0) ? 1 : 0;
    }
    if (p < 0 || nch == 0) return;  // row stays unchanged

    float upd = 0.0f, a = 0.0f;
    if (tid < NBOX) {
        const float sub = ea[((size_t)b * NSEQ + p) * NBOX + tid];
        const float w   = wc[((size_t)b * NSEQ + p) * NBOX + tid];
        upd = sub + (araw[b * NBOX + tid] + (float)nch * EPSV) * w;
        a = fabsf(upd);
    }
    #pragma unroll
    for (int off = 32; off >= 1; off >>= 1)
        a = fmaxf(a, __shfl_down(a, off, 64));
    __shared__ float wmax[4];
    if ((tid & 63) == 0) wmax[tid >> 6] = a;
    __syncthreads();
    float norm = fmaxf(fmaxf(wmax[0], wmax[1]), fmaxf(wmax[2], wmax[3]));
    norm = (norm <= 1.0f) ? 1.0f : norm;
    if (tid < NBOX) {
        float val = upd / norm;
        if (roi_cls[b * NBOX + tid] == -1) val = -1.0f;
        ea[((size_t)b * NSEQ + p) * NBOX + tid] = val;
    }
}

extern "C" void kernel_launch(void* const* d_in, const int* in_sizes, int n_in,
                              void* d_out, int out_size, void* d_ws, size_t ws_size,
                              hipStream_t stream) {
    const int*   trav = (const int*)  d_in[0];
    const int*   adj  = (const int*)  d_in[1];
    const float* ent  = (const float*)d_in[2];
    const float* spo  = (const float*)d_in[3];
    const int*   ctx  = (const int*)  d_in[4];
    const int*   roi  = (const int*)  d_in[5];
    const float* rm   = (const float*)d_in[6];
    const float* wc   = (const float*)d_in[7];

    float* ea = (float*)d_out;

    const bool ws_ok = ws_size >= (MIDX_ELEMS + (size_t)BS * NBOX) * 4;
    int*   midx = (int*)d_ws;
    float* araw = ws_ok ? ((float*)d_ws + MIDX_ELEMS) : (float*)d_ws;

    for (int t = 0; t < MAXLEN; ++t) {
        const int mode = ws_ok ? (t == 0 ? 1 : 2) : 0;
        step_compute<<<BS * TILES, K1T, 0, stream>>>(
            t == 0 ? ent : ea, ea, spo, ctx, roi, rm, trav, adj,
            midx, araw, t, mode);
        step_finalize<<<BS, 256, 0, stream>>>(
            ea, araw, wc, roi, trav, adj, t);
    }
}